// Round 4
// baseline (10666.113 us; speedup 1.0000x reference)
//
#include <hip/hip_runtime.h>
#include <math.h>

// Problem constants (fixed by setup_inputs)
#define NQ   4096     // N source points
#define NK   4096     // M target points
#define DD   256      // feature dim (Ds == Dt)
#define NB   4        // batch
#define ROWS 64       // query rows per block
#define KT   512      // keys per tile (softmax-update granularity)
#define KS   32       // dims staged in LDS per slice
#define NTHR 512
#define QPITCH 260    // floats; 260 % 32 == 4
#define KPITCH 36     // floats; 36 % 32 == 4 -> bank-balanced b128 access

// ---------------------------------------------------------------------------
// Fused kernel: Q = f_src@W^T + b  (phase A, Q kept in LDS)
// then flash-style: S = Q@K^T, online softmax over 512-key tiles,
// pv += p * p_tgt, finally per-block partial sums of
// {sum p_src, sum p_corr, sum p_src x p_corr} atomically accumulated into
// out_acc[b*16 + 0..14].
//
// Inner loop: 8 rows x 8 keys per thread (64 fp32 accumulators) ->
// 16 ds_read_b128 per 256 FMAs: LDS port and VALU co-limiting (1.0 B/FMA).
//
// __launch_bounds__(512, 1): R3 post-mortem — (512,2) made hipcc cap VGPRs
// at 128 (it treats arg2 as min BLOCKS/CU: 16 waves/CU -> 4 waves/SIMD ->
// 512-reg pool/4 = 128), spilling ~100 regs -> 32 GB scratch traffic/launch,
// VALUBusy 4.6%. LDS (152 KB) already limits us to 1 block/CU = 2 waves/SIMD,
// so (512,1) gives the correct 256-reg cap; live-set ~200 fits without spill.
// ---------------------------------------------------------------------------
__global__ __launch_bounds__(NTHR, 1)
void flash_kernel(const float* __restrict__ p_src,
                  const float* __restrict__ f_src,
                  const float* __restrict__ p_tgt,
                  const float* __restrict__ f_tgt,
                  const float* __restrict__ W,
                  const float* __restrict__ bias,
                  float* __restrict__ out_acc)
{
    __shared__ __align__(16) float Qs[ROWS][QPITCH];   // col-swizzled Q tile
    __shared__ __align__(16) float Ks[KT][KPITCH];     // one 32-dim K slice
    __shared__ float PTs[3][KT + 8];                   // p_tgt tile (transposed)
    __shared__ float wred[8][ROWS];                    // per-wave partials
    __shared__ float rowred[ROWS];                     // tile max / tile sum
    __shared__ float fred[8][8][24];                   // final pv partials
    __shared__ float lrun_s[ROWS];

    const int t    = threadIdx.x;
    const int lane = t & 63;
    const int wave = __builtin_amdgcn_readfirstlane(t >> 6);

    // Batch->XCD affinity swizzle (perf heuristic only; any mapping is
    // correct). Assuming dispatch round-robins linear wg across 8 XCDs,
    // b = (wg&7)>>1 pins each batch to one XCD pair, so each XCD's 4 MiB L2
    // holds only its own batch's 4 MB f_tgt panel.
    const int wg   = blockIdx.y * gridDim.x + blockIdx.x;   // 0..255
    const int b    = (wg & 7) >> 1;                          // 0..3
    const int rb   = (wg >> 3) + ((wg & 1) << 5);            // 0..63, bijective
    const int row0 = rb * ROWS;

    // slice s covers keys [(s>>3)*512, ...+512), dims [(s&7)*32, ...+32)
    // thread t stages key row t, all 32 dims (8 x float4).
    auto slice_src = [&](int s) {
        return f_tgt + ((size_t)b * NK + (s >> 3) * KT + t) * DD + (s & 7) * KS;
    };

    // Issue slice-0 K loads early: latency hides under Phase A compute.
    float4 v0[8];
    {
        const float* sp = slice_src(0);
        #pragma unroll
        for (int c = 0; c < 8; ++c) v0[c] = *(const float4*)(sp + 4 * c);
    }

    // ---------------- Phase A: Q tile = f_src @ W^T + bias ----------------
    {
        const int rbase = row0 + wave * 8;   // 8 rows per wave
        const int c0    = lane * 4;          // 4 output cols per thread
        float acc[8][4];
        #pragma unroll
        for (int i = 0; i < 8; ++i)
            #pragma unroll
            for (int j = 0; j < 4; ++j) acc[i][j] = 0.f;

        const float* fs = f_src + ((size_t)b * NQ + rbase) * DD;
        const float* Wp = W + (size_t)c0 * DD;
        for (int k = 0; k < DD; k += 4) {
            float4 w0 = *(const float4*)(Wp + 0 * DD + k);
            float4 w1 = *(const float4*)(Wp + 1 * DD + k);
            float4 w2 = *(const float4*)(Wp + 2 * DD + k);
            float4 w3 = *(const float4*)(Wp + 3 * DD + k);
            #pragma unroll
            for (int i = 0; i < 8; ++i) {
                float4 f = *(const float4*)(fs + i * DD + k);
                acc[i][0] += f.x*w0.x + f.y*w0.y + f.z*w0.z + f.w*w0.w;
                acc[i][1] += f.x*w1.x + f.y*w1.y + f.z*w1.z + f.w*w1.w;
                acc[i][2] += f.x*w2.x + f.y*w2.y + f.z*w2.z + f.w*w2.w;
                acc[i][3] += f.x*w3.x + f.y*w3.y + f.z*w3.z + f.w*w3.w;
            }
        }
        float4 bv = *(const float4*)(bias + c0);
        const int chunk = lane;                      // == c0 >> 2
        const int scol  = 4 * (chunk ^ (wave & 7));  // swizzle key = row>>3
        #pragma unroll
        for (int i = 0; i < 8; ++i) {
            float4 q;
            q.x = acc[i][0] + bv.x;  q.y = acc[i][1] + bv.y;
            q.z = acc[i][2] + bv.z;  q.w = acc[i][3] + bv.w;
            *(float4*)&Qs[wave * 8 + i][scol] = q;
        }
    }

    // ---------------- Prologue: write K slice 0 + PT tile 0 ----------------
    {
        #pragma unroll
        for (int c = 0; c < 8; ++c) *(float4*)&Ks[t][4 * c] = v0[c];
        const float* pp = p_tgt + ((size_t)b * NK + t) * 3;
        PTs[0][t] = pp[0]; PTs[1][t] = pp[1]; PTs[2][t] = pp[2];
    }
    __syncthreads();   // covers Qs writes + slice-0/PT staging

    // thread tiling for S: 8 rows (rg) x 8 keys (mg, strided by 64)
    const int rg = t & 7;     // row group: rows rg*8 + i
    const int mg = t >> 3;    // 0..63: keys mg + 64*j

    float m_run[8], l_run[8], pv[8][3];
    #pragma unroll
    for (int i = 0; i < 8; ++i) {
        m_run[i] = -INFINITY; l_run[i] = 0.f;
        pv[i][0] = pv[i][1] = pv[i][2] = 0.f;
    }
    float S[8][8];

    const int NSLICE = (NK / KT) * (DD / KS);   // 8 tiles x 8 slices = 64
    for (int s = 0; s < NSLICE; ++s) {
        // issue next-slice global loads early (latency hides under compute)
        float4 nv[8];
        float npt[3];
        const bool have_next = (s + 1) < NSLICE;
        if (have_next) {
            const float* sp = slice_src(s + 1);
            #pragma unroll
            for (int c = 0; c < 8; ++c) nv[c] = *(const float4*)(sp + 4 * c);
            if (((s + 1) & 7) == 0) {
                const float* pp = p_tgt +
                    ((size_t)b * NK + ((s + 1) >> 3) * KT + t) * 3;
                npt[0] = pp[0]; npt[1] = pp[1]; npt[2] = pp[2];
            }
        }

        if ((s & 7) == 0) {
            #pragma unroll
            for (int i = 0; i < 8; ++i)
                #pragma unroll
                for (int j = 0; j < 8; ++j) S[i][j] = 0.f;
        }

        // ---- 8x8 fp32 outer-product over this 32-dim slice ----
        #pragma unroll
        for (int kk = 0; kk < KS; kk += 4) {
            const int chunk = ((s & 7) * KS + kk) >> 2;   // global dim / 4
            const int qcol  = 4 * (chunk ^ rg);
            float4 kv[8];
            #pragma unroll
            for (int j = 0; j < 8; ++j)
                kv[j] = *(const float4*)&Ks[mg + 64 * j][kk];
            #pragma unroll
            for (int i = 0; i < 8; ++i) {
                const float4 q = *(const float4*)&Qs[rg * 8 + i][qcol];
                #pragma unroll
                for (int j = 0; j < 8; ++j) {
                    S[i][j] += q.x*kv[j].x + q.y*kv[j].y
                             + q.z*kv[j].z + q.w*kv[j].w;
                }
            }
        }

        // ---------------- tile boundary: online softmax update ----------------
        if ((s & 7) == 7) {
            // 1) row max: local -> within-wave (lanes sharing rg) -> cross-wave
            float mx[8];
            #pragma unroll
            for (int i = 0; i < 8; ++i) {
                float m0 = S[i][0];
                #pragma unroll
                for (int j = 1; j < 8; ++j) m0 = fmaxf(m0, S[i][j]);
                m0 = fmaxf(m0, __shfl_xor(m0, 8));
                m0 = fmaxf(m0, __shfl_xor(m0, 16));
                m0 = fmaxf(m0, __shfl_xor(m0, 32));
                mx[i] = m0;
            }
            if (lane < 8) {
                #pragma unroll
                for (int i = 0; i < 8; ++i) wred[wave][lane * 8 + i] = mx[i];
            }
            __syncthreads();
            if (t < ROWS) {
                float m0 = wred[0][t];
                #pragma unroll
                for (int w = 1; w < 8; ++w) m0 = fmaxf(m0, wred[w][t]);
                rowred[t] = m0;
            }
            __syncthreads();

            // 2) p = exp(S - mnew); pv update; row-sum reduce
            float pt[8][3];
            #pragma unroll
            for (int j = 0; j < 8; ++j)
                #pragma unroll
                for (int c = 0; c < 3; ++c)
                    pt[j][c] = PTs[c][mg + 64 * j];

            float psum[8], scale[8];
            #pragma unroll
            for (int i = 0; i < 8; ++i) {
                const int r = rg * 8 + i;
                const float mnew = fmaxf(m_run[i], rowred[r]);
                scale[i] = __expf(m_run[i] - mnew);
                m_run[i] = mnew;
                float p[8];
                float ps = 0.f;
                #pragma unroll
                for (int j = 0; j < 8; ++j) {
                    p[j] = __expf(S[i][j] - mnew);
                    ps += p[j];
                }
                #pragma unroll
                for (int c = 0; c < 3; ++c) {
                    float a = 0.f;
                    #pragma unroll
                    for (int j = 0; j < 8; ++j) a += p[j] * pt[j][c];
                    pv[i][c] = pv[i][c] * scale[i] + a;
                }
                ps += __shfl_xor(ps, 8);
                ps += __shfl_xor(ps, 16);
                ps += __shfl_xor(ps, 32);
                psum[i] = ps;
            }
            if (lane < 8) {
                #pragma unroll
                for (int i = 0; i < 8; ++i) wred[wave][lane * 8 + i] = psum[i];
            }
            __syncthreads();
            if (t < ROWS) {
                float s0 = wred[0][t];
                #pragma unroll
                for (int w = 1; w < 8; ++w) s0 += wred[w][t];
                rowred[t] = s0;
            }
            __syncthreads();
            #pragma unroll
            for (int i = 0; i < 8; ++i)
                l_run[i] = l_run[i] * scale[i] + rowred[rg * 8 + i];
        }

        __syncthreads();  // everyone done reading Ks / PTs
        if (have_next) {
            #pragma unroll
            for (int c = 0; c < 8; ++c) *(float4*)&Ks[t][4 * c] = nv[c];
            if (((s + 1) & 7) == 0) {
                PTs[0][t] = npt[0]; PTs[1][t] = npt[1]; PTs[2][t] = npt[2];
            }
        }
        __syncthreads();
    }

    // ---------------- final reduction: pv across 64 threads sharing rg ----------------
    #pragma unroll
    for (int i = 0; i < 8; ++i)
        #pragma unroll
        for (int c = 0; c < 3; ++c) {
            float v = pv[i][c];
            v += __shfl_xor(v, 8);
            v += __shfl_xor(v, 16);
            v += __shfl_xor(v, 32);
            pv[i][c] = v;
        }
    if (lane < 8) {
        #pragma unroll
        for (int i = 0; i < 8; ++i)
            #pragma unroll
            for (int c = 0; c < 3; ++c)
                fred[wave][lane][i * 3 + c] = pv[i][c];
        if (wave == 0) {
            #pragma unroll
            for (int i = 0; i < 8; ++i) lrun_s[lane * 8 + i] = l_run[i];
        }
    }
    __syncthreads();

    if (t < ROWS) {
        const int trg = t >> 3, ti = t & 7;
        float pc[3];
        #pragma unroll
        for (int c = 0; c < 3; ++c) {
            float v = 0.f;
            #pragma unroll
            for (int w = 0; w < 8; ++w) v += fred[w][trg][ti * 3 + c];
            pc[c] = v / lrun_s[t];
        }
        const float* ps = p_src + ((size_t)b * NQ + row0 + t) * 3;
        const float sp0 = ps[0], sp1 = ps[1], sp2 = ps[2];
        float vals[15];
        vals[0] = sp0; vals[1] = sp1; vals[2] = sp2;
        vals[3] = pc[0]; vals[4] = pc[1]; vals[5] = pc[2];
        vals[6]  = sp0 * pc[0]; vals[7]  = sp0 * pc[1]; vals[8]  = sp0 * pc[2];
        vals[9]  = sp1 * pc[0]; vals[10] = sp1 * pc[1]; vals[11] = sp1 * pc[2];
        vals[12] = sp2 * pc[0]; vals[13] = sp2 * pc[1]; vals[14] = sp2 * pc[2];
        #pragma unroll
        for (int k2 = 0; k2 < 15; ++k2) {
            float v = vals[k2];
            #pragma unroll
            for (int d = 1; d < 64; d <<= 1) v += __shfl_xor(v, d);
            vals[k2] = v;
        }
        if (t == 0) {
            #pragma unroll
            for (int k2 = 0; k2 < 15; ++k2)
                atomicAdd(&out_acc[b * 16 + k2], vals[k2]);
        }
    }
}

// ---------------------------------------------------------------------------
// Per-batch 3x3 Kabsch: H from accumulated sums, fp64 Jacobi SVD, writes 4x4.
// Reads accumulators from out[b*16+0..14], overwrites out[b*16+0..15].
// ---------------------------------------------------------------------------
__global__ void svd_kernel(float* __restrict__ out)
{
    const int b = threadIdx.x;
    if (b >= NB) return;

    float sbuf[15];
    #pragma unroll
    for (int i = 0; i < 15; ++i) sbuf[i] = out[b * 16 + i];

    const double invN = 1.0 / (double)NQ;
    double Sp[3] = {sbuf[0], sbuf[1], sbuf[2]};
    double Sc[3] = {sbuf[3], sbuf[4], sbuf[5]};
    double H[3][3];
    for (int i = 0; i < 3; ++i)
        for (int j = 0; j < 3; ++j)
            H[i][j] = (double)sbuf[6 + i * 3 + j] - Sp[i] * Sc[j] * invN;
    double cs[3], cc[3];
    for (int i = 0; i < 3; ++i) { cs[i] = Sp[i] * invN; cc[i] = Sc[i] * invN; }

    // A = H^T H (symmetric), Jacobi eigendecomposition -> V, lambda
    double A[3][3];
    for (int i = 0; i < 3; ++i)
        for (int j = 0; j < 3; ++j)
            A[i][j] = H[0][i]*H[0][j] + H[1][i]*H[1][j] + H[2][i]*H[2][j];
    double V[3][3] = {{1,0,0},{0,1,0},{0,0,1}};

    for (int sweep = 0; sweep < 30; ++sweep) {
        for (int pp = 0; pp < 3; ++pp) {
            const int p = (pp == 2) ? 1 : 0;
            const int q = (pp == 0) ? 1 : 2;
            const double apq = A[p][q];
            if (fabs(apq) < 1e-300) continue;
            const double app = A[p][p], aqq = A[q][q];
            const double tau = (aqq - app) / (2.0 * apq);
            const double tt  = (tau >= 0.0 ? 1.0 : -1.0) /
                               (fabs(tau) + sqrt(1.0 + tau * tau));
            const double c  = 1.0 / sqrt(1.0 + tt * tt);
            const double sn = tt * c;
            const int r = 3 - p - q;
            const double arp = A[r][p], arq = A[r][q];
            A[p][p] = app - tt * apq;
            A[q][q] = aqq + tt * apq;
            A[p][q] = A[q][p] = 0.0;
            A[r][p] = A[p][r] = c * arp - sn * arq;
            A[r][q] = A[q][r] = sn * arp + c * arq;
            for (int i = 0; i < 3; ++i) {
                const double vip = V[i][p], viq = V[i][q];
                V[i][p] = c * vip - sn * viq;
                V[i][q] = sn * vip + c * viq;
            }
        }
    }

    // sort eigenpairs descending
    int idx[3] = {0, 1, 2};
    double lam[3] = {A[0][0], A[1][1], A[2][2]};
    if (lam[idx[0]] < lam[idx[1]]) { int u = idx[0]; idx[0] = idx[1]; idx[1] = u; }
    if (lam[idx[0]] < lam[idx[2]]) { int u = idx[0]; idx[0] = idx[2]; idx[2] = u; }
    if (lam[idx[1]] < lam[idx[2]]) { int u = idx[1]; idx[1] = idx[2]; idx[2] = u; }

    double Vs[3][3], sv[3];
    for (int k = 0; k < 3; ++k) {
        for (int i = 0; i < 3; ++i) Vs[i][k] = V[i][idx[k]];
        const double l2 = lam[idx[k]];
        sv[k] = (l2 > 0.0) ? sqrt(l2) : 0.0;
    }

    // U columns: u_k = H v_k / s_k  (cross-product fallback for tiny s2)
    double U[3][3];
    for (int k = 0; k < 3; ++k) {
        double u0 = H[0][0]*Vs[0][k] + H[0][1]*Vs[1][k] + H[0][2]*Vs[2][k];
        double u1 = H[1][0]*Vs[0][k] + H[1][1]*Vs[1][k] + H[1][2]*Vs[2][k];
        double u2 = H[2][0]*Vs[0][k] + H[2][1]*Vs[1][k] + H[2][2]*Vs[2][k];
        double nn = sqrt(u0*u0 + u1*u1 + u2*u2);
        if (k == 2 && (sv[2] <= 1e-10 * sv[0] || nn == 0.0)) {
            u0 = U[1][0]*U[2][1] - U[2][0]*U[1][1];
            u1 = U[2][0]*U[0][1] - U[0][0]*U[2][1];
            u2 = U[0][0]*U[1][1] - U[1][0]*U[0][1];
            nn = sqrt(u0*u0 + u1*u1 + u2*u2);
        }
        const double inv = (nn > 0.0) ? 1.0 / nn : 0.0;
        U[0][k] = u0 * inv; U[1][k] = u1 * inv; U[2][k] = u2 * inv;
    }

    // R = Vs U^T; det<0 -> flip third (smallest-sigma) column of Vs
    double R[3][3];
    for (int i = 0; i < 3; ++i)
        for (int j = 0; j < 3; ++j)
            R[i][j] = Vs[i][0]*U[j][0] + Vs[i][1]*U[j][1] + Vs[i][2]*U[j][2];
    const double det =
          R[0][0]*(R[1][1]*R[2][2] - R[1][2]*R[2][1])
        - R[0][1]*(R[1][0]*R[2][2] - R[1][2]*R[2][0])
        + R[0][2]*(R[1][0]*R[2][1] - R[1][1]*R[2][0]);
    if (det < 0.0)
        for (int i = 0; i < 3; ++i)
            for (int j = 0; j < 3; ++j)
                R[i][j] -= 2.0 * Vs[i][2] * U[j][2];

    double tv[3];
    for (int i = 0; i < 3; ++i)
        tv[i] = cc[i] - (R[i][0]*cs[0] + R[i][1]*cs[1] + R[i][2]*cs[2]);

    for (int i = 0; i < 3; ++i) {
        for (int j = 0; j < 3; ++j) out[b*16 + i*4 + j] = (float)R[i][j];
        out[b*16 + i*4 + 3] = (float)tv[i];
    }
    out[b*16 + 12] = 0.f; out[b*16 + 13] = 0.f;
    out[b*16 + 14] = 0.f; out[b*16 + 15] = 1.f;
}

extern "C" void kernel_launch(void* const* d_in, const int* in_sizes, int n_in,
                              void* d_out, int out_size, void* d_ws, size_t ws_size,
                              hipStream_t stream)
{
    const float* p_src = (const float*)d_in[0];
    const float* f_src = (const float*)d_in[1];
    const float* p_tgt = (const float*)d_in[2];
    const float* f_tgt = (const float*)d_in[3];
    const float* W     = (const float*)d_in[4];
    const float* bias  = (const float*)d_in[5];
    float* out = (float*)d_out;

    // accumulators live in d_out[b*16 + 0..14]; zero them (d_out is poisoned)
    hipMemsetAsync(out, 0, 64 * sizeof(float), stream);

    dim3 grid(NQ / ROWS, NB);   // (64, 4) = 256 blocks
    flash_kernel<<<grid, NTHR, 0, stream>>>(p_src, f_src, p_tgt, f_tgt, W, bias, out);
    svd_kernel<<<1, 64, 0, stream>>>(out);
}

// Round 5
// 10636.030 us; speedup vs baseline: 1.0028x; 1.0028x over previous
//
#include <hip/hip_runtime.h>
#include <math.h>

// Problem constants (fixed by setup_inputs)
#define NQ   4096     // N source points
#define NK   4096     // M target points
#define DD   256      // feature dim (Ds == Dt)
#define NB   4        // batch
#define ROWS 64       // query rows per block
#define KT   512      // keys per tile (softmax-update granularity)
#define KS   32       // dims staged in LDS per slice
#define NTHR 512
#define QPITCH 260    // floats; 260 % 32 == 4
#define KPITCH 36     // floats; 36 % 32 == 4 -> bank-balanced b128 access

// ---------------------------------------------------------------------------
// Fused kernel: Q = f_src@W^T + b  (phase A, Q kept in LDS)
// then flash-style: S = Q@K^T, online softmax over 512-key tiles,
// pv += p * p_tgt, finally per-block partial sums of
// {sum p_src, sum p_corr, sum p_src x p_corr} atomically accumulated into
// out_acc[b*16 + 0..14].
//
// Inner loop: 8 rows x 8 keys per thread (64 fp32 accumulators) ->
// 16 ds_read_b128 per 256 FMAs: LDS port and VALU co-limiting (1.0 B/FMA).
//
// VGPR cap history (R3/R4 post-mortem): __launch_bounds__(512,2) AND (512,1)
// both produced VGPR_Count=128 with ~20 GB/launch scratch-spill writes (the
// 64-reg S tile re-spilled per kk-sweep) -> hipcc ignores launch_bounds arg2;
// the default occupancy heuristic (min 4 waves/EU) caps VGPRs at 512/4=128.
// Fix: set the LLVM attribute directly. amdgpu_waves_per_eu(2,2) -> maxVGPR
// = 512-reg pool / 2 = 256; peak live-set ~184 fits; LDS (152 KB) limits us
// to 1 block/CU = 2 waves/SIMD anyway, so occupancy is unchanged.
// ---------------------------------------------------------------------------
__global__ __launch_bounds__(NTHR)
__attribute__((amdgpu_waves_per_eu(2, 2)))
void flash_kernel(const float* __restrict__ p_src,
                  const float* __restrict__ f_src,
                  const float* __restrict__ p_tgt,
                  const float* __restrict__ f_tgt,
                  const float* __restrict__ W,
                  const float* __restrict__ bias,
                  float* __restrict__ out_acc)
{
    __shared__ __align__(16) float Qs[ROWS][QPITCH];   // col-swizzled Q tile
    __shared__ __align__(16) float Ks[KT][KPITCH];     // one 32-dim K slice
    __shared__ float PTs[3][KT + 8];                   // p_tgt tile (transposed)
    __shared__ float wred[8][ROWS];                    // per-wave partials
    __shared__ float rowred[ROWS];                     // tile max / tile sum
    __shared__ float fred[8][8][24];                   // final pv partials
    __shared__ float lrun_s[ROWS];

    const int t    = threadIdx.x;
    const int lane = t & 63;
    const int wave = __builtin_amdgcn_readfirstlane(t >> 6);

    // Batch->XCD affinity swizzle (perf heuristic only; any mapping is
    // correct). Assuming dispatch round-robins linear wg across 8 XCDs,
    // b = (wg&7)>>1 pins each batch to one XCD pair, so each XCD's 4 MiB L2
    // holds only its own batch's 4 MB f_tgt panel.
    const int wg   = blockIdx.y * gridDim.x + blockIdx.x;   // 0..255
    const int b    = (wg & 7) >> 1;                          // 0..3
    const int rb   = (wg >> 3) + ((wg & 1) << 5);            // 0..63, bijective
    const int row0 = rb * ROWS;

    // slice s covers keys [(s>>3)*512, ...+512), dims [(s&7)*32, ...+32)
    // thread t stages key row t, all 32 dims (8 x float4).
    auto slice_src = [&](int s) {
        return f_tgt + ((size_t)b * NK + (s >> 3) * KT + t) * DD + (s & 7) * KS;
    };

    // Issue slice-0 K loads early: latency hides under Phase A compute.
    float4 v0[8];
    {
        const float* sp = slice_src(0);
        #pragma unroll
        for (int c = 0; c < 8; ++c) v0[c] = *(const float4*)(sp + 4 * c);
    }

    // ---------------- Phase A: Q tile = f_src @ W^T + bias ----------------
    {
        const int rbase = row0 + wave * 8;   // 8 rows per wave
        const int c0    = lane * 4;          // 4 output cols per thread
        float acc[8][4];
        #pragma unroll
        for (int i = 0; i < 8; ++i)
            #pragma unroll
            for (int j = 0; j < 4; ++j) acc[i][j] = 0.f;

        const float* fs = f_src + ((size_t)b * NQ + rbase) * DD;
        const float* Wp = W + (size_t)c0 * DD;
        for (int k = 0; k < DD; k += 4) {
            float4 w0 = *(const float4*)(Wp + 0 * DD + k);
            float4 w1 = *(const float4*)(Wp + 1 * DD + k);
            float4 w2 = *(const float4*)(Wp + 2 * DD + k);
            float4 w3 = *(const float4*)(Wp + 3 * DD + k);
            #pragma unroll
            for (int i = 0; i < 8; ++i) {
                float4 f = *(const float4*)(fs + i * DD + k);
                acc[i][0] += f.x*w0.x + f.y*w0.y + f.z*w0.z + f.w*w0.w;
                acc[i][1] += f.x*w1.x + f.y*w1.y + f.z*w1.z + f.w*w1.w;
                acc[i][2] += f.x*w2.x + f.y*w2.y + f.z*w2.z + f.w*w2.w;
                acc[i][3] += f.x*w3.x + f.y*w3.y + f.z*w3.z + f.w*w3.w;
            }
        }
        float4 bv = *(const float4*)(bias + c0);
        const int chunk = lane;                      // == c0 >> 2
        const int scol  = 4 * (chunk ^ (wave & 7));  // swizzle key = row>>3
        #pragma unroll
        for (int i = 0; i < 8; ++i) {
            float4 q;
            q.x = acc[i][0] + bv.x;  q.y = acc[i][1] + bv.y;
            q.z = acc[i][2] + bv.z;  q.w = acc[i][3] + bv.w;
            *(float4*)&Qs[wave * 8 + i][scol] = q;
        }
    }

    // ---------------- Prologue: write K slice 0 + PT tile 0 ----------------
    {
        #pragma unroll
        for (int c = 0; c < 8; ++c) *(float4*)&Ks[t][4 * c] = v0[c];
        const float* pp = p_tgt + ((size_t)b * NK + t) * 3;
        PTs[0][t] = pp[0]; PTs[1][t] = pp[1]; PTs[2][t] = pp[2];
    }
    __syncthreads();   // covers Qs writes + slice-0/PT staging

    // thread tiling for S: 8 rows (rg) x 8 keys (mg, strided by 64)
    const int rg = t & 7;     // row group: rows rg*8 + i
    const int mg = t >> 3;    // 0..63: keys mg + 64*j

    float m_run[8], l_run[8], pv[8][3];
    #pragma unroll
    for (int i = 0; i < 8; ++i) {
        m_run[i] = -INFINITY; l_run[i] = 0.f;
        pv[i][0] = pv[i][1] = pv[i][2] = 0.f;
    }
    float S[8][8];

    const int NSLICE = (NK / KT) * (DD / KS);   // 8 tiles x 8 slices = 64
    for (int s = 0; s < NSLICE; ++s) {
        // issue next-slice global loads early (latency hides under compute)
        float4 nv[8];
        float npt[3];
        const bool have_next = (s + 1) < NSLICE;
        if (have_next) {
            const float* sp = slice_src(s + 1);
            #pragma unroll
            for (int c = 0; c < 8; ++c) nv[c] = *(const float4*)(sp + 4 * c);
            if (((s + 1) & 7) == 0) {
                const float* pp = p_tgt +
                    ((size_t)b * NK + ((s + 1) >> 3) * KT + t) * 3;
                npt[0] = pp[0]; npt[1] = pp[1]; npt[2] = pp[2];
            }
        }

        if ((s & 7) == 0) {
            #pragma unroll
            for (int i = 0; i < 8; ++i)
                #pragma unroll
                for (int j = 0; j < 8; ++j) S[i][j] = 0.f;
        }

        // ---- 8x8 fp32 outer-product over this 32-dim slice ----
        #pragma unroll
        for (int kk = 0; kk < KS; kk += 4) {
            const int chunk = ((s & 7) * KS + kk) >> 2;   // global dim / 4
            const int qcol  = 4 * (chunk ^ rg);
            float4 kv[8];
            #pragma unroll
            for (int j = 0; j < 8; ++j)
                kv[j] = *(const float4*)&Ks[mg + 64 * j][kk];
            #pragma unroll
            for (int i = 0; i < 8; ++i) {
                const float4 q = *(const float4*)&Qs[rg * 8 + i][qcol];
                #pragma unroll
                for (int j = 0; j < 8; ++j) {
                    S[i][j] += q.x*kv[j].x + q.y*kv[j].y
                             + q.z*kv[j].z + q.w*kv[j].w;
                }
            }
        }

        // ---------------- tile boundary: online softmax update ----------------
        if ((s & 7) == 7) {
            // 1) row max: local -> within-wave (lanes sharing rg) -> cross-wave
            float mx[8];
            #pragma unroll
            for (int i = 0; i < 8; ++i) {
                float m0 = S[i][0];
                #pragma unroll
                for (int j = 1; j < 8; ++j) m0 = fmaxf(m0, S[i][j]);
                m0 = fmaxf(m0, __shfl_xor(m0, 8));
                m0 = fmaxf(m0, __shfl_xor(m0, 16));
                m0 = fmaxf(m0, __shfl_xor(m0, 32));
                mx[i] = m0;
            }
            if (lane < 8) {
                #pragma unroll
                for (int i = 0; i < 8; ++i) wred[wave][lane * 8 + i] = mx[i];
            }
            __syncthreads();
            if (t < ROWS) {
                float m0 = wred[0][t];
                #pragma unroll
                for (int w = 1; w < 8; ++w) m0 = fmaxf(m0, wred[w][t]);
                rowred[t] = m0;
            }
            __syncthreads();

            // 2) p = exp(S - mnew); pv update; row-sum reduce
            float pt[8][3];
            #pragma unroll
            for (int j = 0; j < 8; ++j)
                #pragma unroll
                for (int c = 0; c < 3; ++c)
                    pt[j][c] = PTs[c][mg + 64 * j];

            float psum[8], scale[8];
            #pragma unroll
            for (int i = 0; i < 8; ++i) {
                const int r = rg * 8 + i;
                const float mnew = fmaxf(m_run[i], rowred[r]);
                scale[i] = __expf(m_run[i] - mnew);
                m_run[i] = mnew;
                float p[8];
                float ps = 0.f;
                #pragma unroll
                for (int j = 0; j < 8; ++j) {
                    p[j] = __expf(S[i][j] - mnew);
                    ps += p[j];
                }
                #pragma unroll
                for (int c = 0; c < 3; ++c) {
                    float a = 0.f;
                    #pragma unroll
                    for (int j = 0; j < 8; ++j) a += p[j] * pt[j][c];
                    pv[i][c] = pv[i][c] * scale[i] + a;
                }
                ps += __shfl_xor(ps, 8);
                ps += __shfl_xor(ps, 16);
                ps += __shfl_xor(ps, 32);
                psum[i] = ps;
            }
            if (lane < 8) {
                #pragma unroll
                for (int i = 0; i < 8; ++i) wred[wave][lane * 8 + i] = psum[i];
            }
            __syncthreads();
            if (t < ROWS) {
                float s0 = wred[0][t];
                #pragma unroll
                for (int w = 1; w < 8; ++w) s0 += wred[w][t];
                rowred[t] = s0;
            }
            __syncthreads();
            #pragma unroll
            for (int i = 0; i < 8; ++i)
                l_run[i] = l_run[i] * scale[i] + rowred[rg * 8 + i];
        }

        __syncthreads();  // everyone done reading Ks / PTs
        if (have_next) {
            #pragma unroll
            for (int c = 0; c < 8; ++c) *(float4*)&Ks[t][4 * c] = nv[c];
            if (((s + 1) & 7) == 0) {
                PTs[0][t] = npt[0]; PTs[1][t] = npt[1]; PTs[2][t] = npt[2];
            }
        }
        __syncthreads();
    }

    // ---------------- final reduction: pv across 64 threads sharing rg ----------------
    #pragma unroll
    for (int i = 0; i < 8; ++i)
        #pragma unroll
        for (int c = 0; c < 3; ++c) {
            float v = pv[i][c];
            v += __shfl_xor(v, 8);
            v += __shfl_xor(v, 16);
            v += __shfl_xor(v, 32);
            pv[i][c] = v;
        }
    if (lane < 8) {
        #pragma unroll
        for (int i = 0; i < 8; ++i)
            #pragma unroll
            for (int c = 0; c < 3; ++c)
                fred[wave][lane][i * 3 + c] = pv[i][c];
        if (wave == 0) {
            #pragma unroll
            for (int i = 0; i < 8; ++i) lrun_s[lane * 8 + i] = l_run[i];
        }
    }
    __syncthreads();

    if (t < ROWS) {
        const int trg = t >> 3, ti = t & 7;
        float pc[3];
        #pragma unroll
        for (int c = 0; c < 3; ++c) {
            float v = 0.f;
            #pragma unroll
            for (int w = 0; w < 8; ++w) v += fred[w][trg][ti * 3 + c];
            pc[c] = v / lrun_s[t];
        }
        const float* ps = p_src + ((size_t)b * NQ + row0 + t) * 3;
        const float sp0 = ps[0], sp1 = ps[1], sp2 = ps[2];
        float vals[15];
        vals[0] = sp0; vals[1] = sp1; vals[2] = sp2;
        vals[3] = pc[0]; vals[4] = pc[1]; vals[5] = pc[2];
        vals[6]  = sp0 * pc[0]; vals[7]  = sp0 * pc[1]; vals[8]  = sp0 * pc[2];
        vals[9]  = sp1 * pc[0]; vals[10] = sp1 * pc[1]; vals[11] = sp1 * pc[2];
        vals[12] = sp2 * pc[0]; vals[13] = sp2 * pc[1]; vals[14] = sp2 * pc[2];
        #pragma unroll
        for (int k2 = 0; k2 < 15; ++k2) {
            float v = vals[k2];
            #pragma unroll
            for (int d = 1; d < 64; d <<= 1) v += __shfl_xor(v, d);
            vals[k2] = v;
        }
        if (t == 0) {
            #pragma unroll
            for (int k2 = 0; k2 < 15; ++k2)
                atomicAdd(&out_acc[b * 16 + k2], vals[k2]);
        }
    }
}

// ---------------------------------------------------------------------------
// Per-batch 3x3 Kabsch: H from accumulated sums, fp64 Jacobi SVD, writes 4x4.
// Reads accumulators from out[b*16+0..14], overwrites out[b*16+0..15].
// ---------------------------------------------------------------------------
__global__ void svd_kernel(float* __restrict__ out)
{
    const int b = threadIdx.x;
    if (b >= NB) return;

    float sbuf[15];
    #pragma unroll
    for (int i = 0; i < 15; ++i) sbuf[i] = out[b * 16 + i];

    const double invN = 1.0 / (double)NQ;
    double Sp[3] = {sbuf[0], sbuf[1], sbuf[2]};
    double Sc[3] = {sbuf[3], sbuf[4], sbuf[5]};
    double H[3][3];
    for (int i = 0; i < 3; ++i)
        for (int j = 0; j < 3; ++j)
            H[i][j] = (double)sbuf[6 + i * 3 + j] - Sp[i] * Sc[j] * invN;
    double cs[3], cc[3];
    for (int i = 0; i < 3; ++i) { cs[i] = Sp[i] * invN; cc[i] = Sc[i] * invN; }

    // A = H^T H (symmetric), Jacobi eigendecomposition -> V, lambda
    double A[3][3];
    for (int i = 0; i < 3; ++i)
        for (int j = 0; j < 3; ++j)
            A[i][j] = H[0][i]*H[0][j] + H[1][i]*H[1][j] + H[2][i]*H[2][j];
    double V[3][3] = {{1,0,0},{0,1,0},{0,0,1}};

    for (int sweep = 0; sweep < 30; ++sweep) {
        for (int pp = 0; pp < 3; ++pp) {
            const int p = (pp == 2) ? 1 : 0;
            const int q = (pp == 0) ? 1 : 2;
            const double apq = A[p][q];
            if (fabs(apq) < 1e-300) continue;
            const double app = A[p][p], aqq = A[q][q];
            const double tau = (aqq - app) / (2.0 * apq);
            const double tt  = (tau >= 0.0 ? 1.0 : -1.0) /
                               (fabs(tau) + sqrt(1.0 + tau * tau));
            const double c  = 1.0 / sqrt(1.0 + tt * tt);
            const double sn = tt * c;
            const int r = 3 - p - q;
            const double arp = A[r][p], arq = A[r][q];
            A[p][p] = app - tt * apq;
            A[q][q] = aqq + tt * apq;
            A[p][q] = A[q][p] = 0.0;
            A[r][p] = A[p][r] = c * arp - sn * arq;
            A[r][q] = A[q][r] = sn * arp + c * arq;
            for (int i = 0; i < 3; ++i) {
                const double vip = V[i][p], viq = V[i][q];
                V[i][p] = c * vip - sn * viq;
                V[i][q] = sn * vip + c * viq;
            }
        }
    }

    // sort eigenpairs descending
    int idx[3] = {0, 1, 2};
    double lam[3] = {A[0][0], A[1][1], A[2][2]};
    if (lam[idx[0]] < lam[idx[1]]) { int u = idx[0]; idx[0] = idx[1]; idx[1] = u; }
    if (lam[idx[0]] < lam[idx[2]]) { int u = idx[0]; idx[0] = idx[2]; idx[2] = u; }
    if (lam[idx[1]] < lam[idx[2]]) { int u = idx[1]; idx[1] = idx[2]; idx[2] = u; }

    double Vs[3][3], sv[3];
    for (int k = 0; k < 3; ++k) {
        for (int i = 0; i < 3; ++i) Vs[i][k] = V[i][idx[k]];
        const double l2 = lam[idx[k]];
        sv[k] = (l2 > 0.0) ? sqrt(l2) : 0.0;
    }

    // U columns: u_k = H v_k / s_k  (cross-product fallback for tiny s2)
    double U[3][3];
    for (int k = 0; k < 3; ++k) {
        double u0 = H[0][0]*Vs[0][k] + H[0][1]*Vs[1][k] + H[0][2]*Vs[2][k];
        double u1 = H[1][0]*Vs[0][k] + H[1][1]*Vs[1][k] + H[1][2]*Vs[2][k];
        double u2 = H[2][0]*Vs[0][k] + H[2][1]*Vs[1][k] + H[2][2]*Vs[2][k];
        double nn = sqrt(u0*u0 + u1*u1 + u2*u2);
        if (k == 2 && (sv[2] <= 1e-10 * sv[0] || nn == 0.0)) {
            u0 = U[1][0]*U[2][1] - U[2][0]*U[1][1];
            u1 = U[2][0]*U[0][1] - U[0][0]*U[2][1];
            u2 = U[0][0]*U[1][1] - U[1][0]*U[0][1];
            nn = sqrt(u0*u0 + u1*u1 + u2*u2);
        }
        const double inv = (nn > 0.0) ? 1.0 / nn : 0.0;
        U[0][k] = u0 * inv; U[1][k] = u1 * inv; U[2][k] = u2 * inv;
    }

    // R = Vs U^T; det<0 -> flip third (smallest-sigma) column of Vs
    double R[3][3];
    for (int i = 0; i < 3; ++i)
        for (int j = 0; j < 3; ++j)
            R[i][j] = Vs[i][0]*U[j][0] + Vs[i][1]*U[j][1] + Vs[i][2]*U[j][2];
    const double det =
          R[0][0]*(R[1][1]*R[2][2] - R[1][2]*R[2][1])
        - R[0][1]*(R[1][0]*R[2][2] - R[1][2]*R[2][0])
        + R[0][2]*(R[1][0]*R[2][1] - R[1][1]*R[2][0]);
    if (det < 0.0)
        for (int i = 0; i < 3; ++i)
            for (int j = 0; j < 3; ++j)
                R[i][j] -= 2.0 * Vs[i][2] * U[j][2];

    double tv[3];
    for (int i = 0; i < 3; ++i)
        tv[i] = cc[i] - (R[i][0]*cs[0] + R[i][1]*cs[1] + R[i][2]*cs[2]);

    for (int i = 0; i < 3; ++i) {
        for (int j = 0; j < 3; ++j) out[b*16 + i*4 + j] = (float)R[i][j];
        out[b*16 + i*4 + 3] = (float)tv[i];
    }
    out[b*16 + 12] = 0.f; out[b*16 + 13] = 0.f;
    out[b*16 + 14] = 0.f; out[b*16 + 15] = 1.f;
}

extern "C" void kernel_launch(void* const* d_in, const int* in_sizes, int n_in,
                              void* d_out, int out_size, void* d_ws, size_t ws_size,
                              hipStream_t stream)
{
    const float* p_src = (const float*)d_in[0];
    const float* f_src = (const float*)d_in[1];
    const float* p_tgt = (const float*)d_in[2];
    const float* f_tgt = (const float*)d_in[3];
    const float* W     = (const float*)d_in[4];
    const float* bias  = (const float*)d_in[5];
    float* out = (float*)d_out;

    // accumulators live in d_out[b*16 + 0..14]; zero them (d_out is poisoned)
    hipMemsetAsync(out, 0, 64 * sizeof(float), stream);

    dim3 grid(NQ / ROWS, NB);   // (64, 4) = 256 blocks
    flash_kernel<<<grid, NTHR, 0, stream>>>(p_src, f_src, p_tgt, f_tgt, W, bias, out);
    svd_kernel<<<1, 64, 0, stream>>>(out);
}

// Round 6
// 419.625 us; speedup vs baseline: 25.4182x; 25.3465x over previous
//
#include <hip/hip_runtime.h>
#include <math.h>

// Problem constants (fixed by setup_inputs)
#define NQ   4096
#define NK   4096
#define DD   256
#define NB   4
#define ROWS 64      // query rows per block
#define KT   256     // keys per K-tile
#define NTILE (NK / KT)   // 16
#define NTHR 512

typedef __attribute__((ext_vector_type(8))) short    bf16x8;
typedef __attribute__((ext_vector_type(8))) unsigned short u16x8;
typedef __attribute__((ext_vector_type(4))) unsigned short u16x4;
typedef __attribute__((ext_vector_type(4))) float    f32x4;

__device__ __forceinline__ unsigned short f2bf(float x) {
    union { float f; unsigned u; } v; v.f = x;
    unsigned r = v.u + 0x7fffu + ((v.u >> 16) & 1u);   // RN-even
    return (unsigned short)(r >> 16);
}
__device__ __forceinline__ float bf2f(unsigned short h) {
    union { unsigned u; float f; } v; v.u = ((unsigned)h) << 16;
    return v.f;
}

// ---------------------------------------------------------------------------
// MFMA flash kernel (split-bf16, 3-pass: QhiKhi + QhiKlo + QloKhi).
// Per block: 64 Q-rows. Phase A computes Q=f_src@W^T+b in fp32 (VALU), splits
// into Qhi (LDS, transient; loaded once into registers as A-frags) and Qlo
// (LDS, persistent). Main loop: 16 K-tiles of 256 keys; each tile stages
// Khi/Klo in 4 dim-slices of 64, runs 16x16x32 bf16 MFMAs, then an online-
// softmax finish on the fp32 accumulators. pv/l are kept as per-lane partials
// (deferred reduction); only the row-max is reduced per tile.
// Wave layout: 8 waves = 2 row-groups(32 rows) x 4 key-groups(64 keys).
// All LDS tiles XOR-swizzled: idx ^= (row&7)<<3  (16B-window spread, G4).
// VGPR budget: Ahi(64)+acc(32) are MFMA operands -> AGPR-eligible on gfx950
// unified file; ~96 arch VGPRs remain -> fits the observed hard 128 cap.
// ---------------------------------------------------------------------------
__global__ __launch_bounds__(NTHR)
void flash_kernel(const float* __restrict__ p_src,
                  const float* __restrict__ f_src,
                  const float* __restrict__ p_tgt,
                  const float* __restrict__ f_tgt,
                  const float* __restrict__ W,
                  const float* __restrict__ bias,
                  float* __restrict__ out_acc)
{
    __shared__ __align__(16) unsigned short Khi[KT * 64];   // also Qhi staging
    __shared__ __align__(16) unsigned short Klo[KT * 64];
    __shared__ __align__(16) unsigned short Qlo[ROWS * DD];
    __shared__ float PTs[3][KT + 8];
    __shared__ float wred[4][ROWS];
    __shared__ float rowred[ROWS];
    __shared__ float fred[4][ROWS][4];

    const int t    = threadIdx.x;
    const int lane = t & 63;
    const int wave = __builtin_amdgcn_readfirstlane(t >> 6);
    const int rg   = wave >> 2;        // row-group: rows rg*32 .. +32
    const int kg   = wave & 3;         // key-group: keys kg*64 .. +64
    const int l15  = lane & 15;
    const int l4   = lane >> 4;        // 0..3

    // Batch->XCD affinity swizzle (heuristic only)
    const int wg   = blockIdx.y * gridDim.x + blockIdx.x;   // 0..255
    const int b    = (wg & 7) >> 1;
    const int rb   = (wg >> 3) + ((wg & 1) << 5);
    const int row0 = rb * ROWS;

    // ---------------- Phase A: Q = f_src @ W^T + bias (fp32 VALU) ----------
    {
        const int rbase = row0 + wave * 8;
        const int c0    = lane * 4;
        float acc[8][4];
        #pragma unroll
        for (int i = 0; i < 8; ++i)
            #pragma unroll
            for (int j = 0; j < 4; ++j) acc[i][j] = 0.f;

        const float* fs = f_src + ((size_t)b * NQ + rbase) * DD;
        const float* Wp = W + (size_t)c0 * DD;
        for (int k = 0; k < DD; k += 4) {
            float4 w0 = *(const float4*)(Wp + 0 * DD + k);
            float4 w1 = *(const float4*)(Wp + 1 * DD + k);
            float4 w2 = *(const float4*)(Wp + 2 * DD + k);
            float4 w3 = *(const float4*)(Wp + 3 * DD + k);
            #pragma unroll
            for (int i = 0; i < 8; ++i) {
                float4 f = *(const float4*)(fs + i * DD + k);
                acc[i][0] += f.x*w0.x + f.y*w0.y + f.z*w0.z + f.w*w0.w;
                acc[i][1] += f.x*w1.x + f.y*w1.y + f.z*w1.z + f.w*w1.w;
                acc[i][2] += f.x*w2.x + f.y*w2.y + f.z*w2.z + f.w*w2.w;
                acc[i][3] += f.x*w3.x + f.y*w3.y + f.z*w3.z + f.w*w3.w;
            }
        }
        float4 bv = *(const float4*)(bias + c0);
        #pragma unroll
        for (int i = 0; i < 8; ++i) {
            const int r = wave * 8 + i;              // local row 0..63
            float q[4] = { acc[i][0] + bv.x, acc[i][1] + bv.y,
                           acc[i][2] + bv.z, acc[i][3] + bv.w };
            u16x4 hi, lo;
            #pragma unroll
            for (int j = 0; j < 4; ++j) {
                unsigned short h = f2bf(q[j]);
                hi[j] = h;
                lo[j] = f2bf(q[j] - bf2f(h));
            }
            const int idx = (r * DD + c0) ^ ((r & 7) << 3);
            *(u16x4*)&Khi[idx] = hi;      // Qhi staged in Khi buffer
            *(u16x4*)&Qlo[idx] = lo;
        }
    }
    __syncthreads();

    // ---------------- Load Ahi fragments (held in registers) ---------------
    // A-frag (16x16x32): lane holds A[m][k], m = lane&15, k = (lane>>4)*8+e.
    bf16x8 ahi[2][8];
    #pragma unroll
    for (int rf = 0; rf < 2; ++rf) {
        const int row = rg * 32 + rf * 16 + l15;
        #pragma unroll
        for (int c = 0; c < 8; ++c) {
            const int d = c * 32 + l4 * 8;
            const int idx = (row * DD + d) ^ ((row & 7) << 3);
            ahi[rf][c] = *(const bf16x8*)&Khi[idx];
        }
    }
    __syncthreads();   // done reading Qhi; Khi free for K staging

    // ---------------- per-lane online-softmax state ------------------------
    float m_run[2][4], l_run[2][4], pv[2][4][3];
    #pragma unroll
    for (int rf = 0; rf < 2; ++rf)
        #pragma unroll
        for (int j = 0; j < 4; ++j) {
            m_run[rf][j] = -INFINITY; l_run[rf][j] = 0.f;
            pv[rf][j][0] = pv[rf][j][1] = pv[rf][j][2] = 0.f;
        }

    const int skey = t >> 1;            // staging: key row 0..255
    const int sdb  = (t & 1) * 32;      // staging: dim offset 0 or 32

    for (int tile = 0; tile < NTILE; ++tile) {
        f32x4 acc[2][4];
        #pragma unroll
        for (int rf = 0; rf < 2; ++rf)
            #pragma unroll
            for (int cf = 0; cf < 4; ++cf)
                acc[rf][cf] = (f32x4){0.f, 0.f, 0.f, 0.f};

        #pragma unroll
        for (int ds = 0; ds < 4; ++ds) {
            // ---- stage K-slice: 256 keys x 64 dims -> Khi/Klo (swizzled) ----
            {
                const float* src = f_tgt +
                    ((size_t)b * NK + tile * KT + skey) * DD + ds * 64 + sdb;
                #pragma unroll
                for (int h = 0; h < 2; ++h) {
                    float4 f0 = *(const float4*)(src + h * 16 + 0);
                    float4 f1 = *(const float4*)(src + h * 16 + 4);
                    float4 f2 = *(const float4*)(src + h * 16 + 8);
                    float4 f3 = *(const float4*)(src + h * 16 + 12);
                    float v[16] = { f0.x,f0.y,f0.z,f0.w, f1.x,f1.y,f1.z,f1.w,
                                    f2.x,f2.y,f2.z,f2.w, f3.x,f3.y,f3.z,f3.w };
                    u16x8 hi0, hi1, lo0, lo1;
                    #pragma unroll
                    for (int e = 0; e < 8; ++e) {
                        unsigned short h0 = f2bf(v[e]);
                        unsigned short h1 = f2bf(v[8 + e]);
                        hi0[e] = h0; hi1[e] = h1;
                        lo0[e] = f2bf(v[e]     - bf2f(h0));
                        lo1[e] = f2bf(v[8 + e] - bf2f(h1));
                    }
                    const int d0 = sdb + h * 16;
                    const int ia = (skey * 64 + d0)     ^ ((skey & 7) << 3);
                    const int ib = (skey * 64 + d0 + 8) ^ ((skey & 7) << 3);
                    *(u16x8*)&Khi[ia] = hi0;  *(u16x8*)&Khi[ib] = hi1;
                    *(u16x8*)&Klo[ia] = lo0;  *(u16x8*)&Klo[ib] = lo1;
                }
                if (ds == 0 && t < KT) {
                    const float* pp = p_tgt + ((size_t)b * NK + tile * KT + t) * 3;
                    PTs[0][t] = pp[0]; PTs[1][t] = pp[1]; PTs[2][t] = pp[2];
                }
            }
            __syncthreads();

            // ---- MFMA sweeps over this 64-dim slice (2 ksteps of 32) ----
            #pragma unroll
            for (int kstep = 0; kstep < 2; ++kstep) {
                const int chunk = ds * 2 + kstep;        // compile-time
                bf16x8 bhi[4], blo[4], alo[2];
                #pragma unroll
                for (int cf = 0; cf < 4; ++cf) {
                    const int key = kg * 64 + cf * 16 + l15;
                    const int dl  = kstep * 32 + l4 * 8;
                    const int idx = (key * 64 + dl) ^ ((key & 7) << 3);
                    bhi[cf] = *(const bf16x8*)&Khi[idx];
                    blo[cf] = *(const bf16x8*)&Klo[idx];
                }
                #pragma unroll
                for (int rf = 0; rf < 2; ++rf) {
                    const int row = rg * 32 + rf * 16 + l15;
                    const int d   = ds * 64 + kstep * 32 + l4 * 8;
                    const int idx = (row * DD + d) ^ ((row & 7) << 3);
                    alo[rf] = *(const bf16x8*)&Qlo[idx];
                }
                #pragma unroll
                for (int rf = 0; rf < 2; ++rf)
                    #pragma unroll
                    for (int cf = 0; cf < 4; ++cf) {
                        acc[rf][cf] = __builtin_amdgcn_mfma_f32_16x16x32_bf16(
                            ahi[rf][chunk], bhi[cf], acc[rf][cf], 0, 0, 0);
                        acc[rf][cf] = __builtin_amdgcn_mfma_f32_16x16x32_bf16(
                            ahi[rf][chunk], blo[cf], acc[rf][cf], 0, 0, 0);
                        acc[rf][cf] = __builtin_amdgcn_mfma_f32_16x16x32_bf16(
                            alo[rf],        bhi[cf], acc[rf][cf], 0, 0, 0);
                    }
            }
            __syncthreads();   // before restaging Khi/Klo
        }

        // ---------------- online-softmax finish for this 256-key tile -------
        // C/D layout (m89-verified): col = lane&15, row = (lane>>4)*4 + reg.
        #pragma unroll
        for (int rf = 0; rf < 2; ++rf) {
            #pragma unroll
            for (int j = 0; j < 4; ++j) {
                float m0 = fmaxf(fmaxf(acc[rf][0][j], acc[rf][1][j]),
                                 fmaxf(acc[rf][2][j], acc[rf][3][j]));
                m0 = fmaxf(m0, __shfl_xor(m0, 1));
                m0 = fmaxf(m0, __shfl_xor(m0, 2));
                m0 = fmaxf(m0, __shfl_xor(m0, 4));
                m0 = fmaxf(m0, __shfl_xor(m0, 8));
                if (l15 == 0) wred[kg][rg * 32 + rf * 16 + l4 * 4 + j] = m0;
            }
        }
        __syncthreads();
        if (t < ROWS) {
            float m0 = wred[0][t];
            m0 = fmaxf(m0, wred[1][t]);
            m0 = fmaxf(m0, wred[2][t]);
            m0 = fmaxf(m0, wred[3][t]);
            rowred[t] = m0;
        }
        __syncthreads();

        float pt[4][3];
        #pragma unroll
        for (int cf = 0; cf < 4; ++cf) {
            const int key = kg * 64 + cf * 16 + l15;
            pt[cf][0] = PTs[0][key]; pt[cf][1] = PTs[1][key]; pt[cf][2] = PTs[2][key];
        }
        #pragma unroll
        for (int rf = 0; rf < 2; ++rf) {
            #pragma unroll
            for (int j = 0; j < 4; ++j) {
                const int row = rg * 32 + rf * 16 + l4 * 4 + j;
                const float mnew = fmaxf(m_run[rf][j], rowred[row]);
                const float scale = __expf(m_run[rf][j] - mnew);
                m_run[rf][j] = mnew;
                float ps = 0.f, a0 = 0.f, a1 = 0.f, a2 = 0.f;
                #pragma unroll
                for (int cf = 0; cf < 4; ++cf) {
                    const float p = __expf(acc[rf][cf][j] - mnew);
                    ps += p;
                    a0 += p * pt[cf][0]; a1 += p * pt[cf][1]; a2 += p * pt[cf][2];
                }
                l_run[rf][j] = l_run[rf][j] * scale + ps;
                pv[rf][j][0] = pv[rf][j][0] * scale + a0;
                pv[rf][j][1] = pv[rf][j][1] * scale + a1;
                pv[rf][j][2] = pv[rf][j][2] * scale + a2;
            }
        }
        __syncthreads();   // protect PTs/wred before next tile's staging
    }

    // ---------------- epilogue: reduce pv/l, then 15 global sums ------------
    #pragma unroll
    for (int rf = 0; rf < 2; ++rf)
        #pragma unroll
        for (int j = 0; j < 4; ++j) {
            float lv = l_run[rf][j];
            float p0 = pv[rf][j][0], p1 = pv[rf][j][1], p2 = pv[rf][j][2];
            #pragma unroll
            for (int d = 1; d < 16; d <<= 1) {
                lv += __shfl_xor(lv, d);
                p0 += __shfl_xor(p0, d);
                p1 += __shfl_xor(p1, d);
                p2 += __shfl_xor(p2, d);
            }
            if (l15 == 0) {
                const int row = rg * 32 + rf * 16 + l4 * 4 + j;
                fred[kg][row][0] = lv;
                fred[kg][row][1] = p0; fred[kg][row][2] = p1; fred[kg][row][3] = p2;
            }
        }
    __syncthreads();

    if (t < ROWS) {
        float lv = fred[0][t][0] + fred[1][t][0] + fred[2][t][0] + fred[3][t][0];
        float pc[3];
        #pragma unroll
        for (int c = 0; c < 3; ++c)
            pc[c] = (fred[0][t][1+c] + fred[1][t][1+c] +
                     fred[2][t][1+c] + fred[3][t][1+c]) / lv;

        const float* ps = p_src + ((size_t)b * NQ + row0 + t) * 3;
        const float sp0 = ps[0], sp1 = ps[1], sp2 = ps[2];
        float vals[15];
        vals[0] = sp0; vals[1] = sp1; vals[2] = sp2;
        vals[3] = pc[0]; vals[4] = pc[1]; vals[5] = pc[2];
        vals[6]  = sp0 * pc[0]; vals[7]  = sp0 * pc[1]; vals[8]  = sp0 * pc[2];
        vals[9]  = sp1 * pc[0]; vals[10] = sp1 * pc[1]; vals[11] = sp1 * pc[2];
        vals[12] = sp2 * pc[0]; vals[13] = sp2 * pc[1]; vals[14] = sp2 * pc[2];
        #pragma unroll
        for (int k2 = 0; k2 < 15; ++k2) {
            float v = vals[k2];
            #pragma unroll
            for (int d = 1; d < 64; d <<= 1) v += __shfl_xor(v, d);
            vals[k2] = v;
        }
        if (t == 0) {
            #pragma unroll
            for (int k2 = 0; k2 < 15; ++k2)
                atomicAdd(&out_acc[b * 16 + k2], vals[k2]);
        }
    }
}

// ---------------------------------------------------------------------------
// Per-batch 3x3 Kabsch: fp64 Jacobi SVD (unchanged; validated absmax=0.0)
// ---------------------------------------------------------------------------
__global__ void svd_kernel(float* __restrict__ out)
{
    const int b = threadIdx.x;
    if (b >= NB) return;

    float sbuf[15];
    #pragma unroll
    for (int i = 0; i < 15; ++i) sbuf[i] = out[b * 16 + i];

    const double invN = 1.0 / (double)NQ;
    double Sp[3] = {sbuf[0], sbuf[1], sbuf[2]};
    double Sc[3] = {sbuf[3], sbuf[4], sbuf[5]};
    double H[3][3];
    for (int i = 0; i < 3; ++i)
        for (int j = 0; j < 3; ++j)
            H[i][j] = (double)sbuf[6 + i * 3 + j] - Sp[i] * Sc[j] * invN;
    double cs[3], cc[3];
    for (int i = 0; i < 3; ++i) { cs[i] = Sp[i] * invN; cc[i] = Sc[i] * invN; }

    double A[3][3];
    for (int i = 0; i < 3; ++i)
        for (int j = 0; j < 3; ++j)
            A[i][j] = H[0][i]*H[0][j] + H[1][i]*H[1][j] + H[2][i]*H[2][j];
    double V[3][3] = {{1,0,0},{0,1,0},{0,0,1}};

    for (int sweep = 0; sweep < 30; ++sweep) {
        for (int pp = 0; pp < 3; ++pp) {
            const int p = (pp == 2) ? 1 : 0;
            const int q = (pp == 0) ? 1 : 2;
            const double apq = A[p][q];
            if (fabs(apq) < 1e-300) continue;
            const double app = A[p][p], aqq = A[q][q];
            const double tau = (aqq - app) / (2.0 * apq);
            const double tt  = (tau >= 0.0 ? 1.0 : -1.0) /
                               (fabs(tau) + sqrt(1.0 + tau * tau));
            const double c  = 1.0 / sqrt(1.0 + tt * tt);
            const double sn = tt * c;
            const int r = 3 - p - q;
            const double arp = A[r][p], arq = A[r][q];
            A[p][p] = app - tt * apq;
            A[q][q] = aqq + tt * apq;
            A[p][q] = A[q][p] = 0.0;
            A[r][p] = A[p][r] = c * arp - sn * arq;
            A[r][q] = A[q][r] = sn * arp + c * arq;
            for (int i = 0; i < 3; ++i) {
                const double vip = V[i][p], viq = V[i][q];
                V[i][p] = c * vip - sn * viq;
                V[i][q] = sn * vip + c * viq;
            }
        }
    }

    int idx[3] = {0, 1, 2};
    double lam[3] = {A[0][0], A[1][1], A[2][2]};
    if (lam[idx[0]] < lam[idx[1]]) { int u = idx[0]; idx[0] = idx[1]; idx[1] = u; }
    if (lam[idx[0]] < lam[idx[2]]) { int u = idx[0]; idx[0] = idx[2]; idx[2] = u; }
    if (lam[idx[1]] < lam[idx[2]]) { int u = idx[1]; idx[1] = idx[2]; idx[2] = u; }

    double Vs[3][3], sv[3];
    for (int k = 0; k < 3; ++k) {
        for (int i = 0; i < 3; ++i) Vs[i][k] = V[i][idx[k]];
        const double l2 = lam[idx[k]];
        sv[k] = (l2 > 0.0) ? sqrt(l2) : 0.0;
    }

    double U[3][3];
    for (int k = 0; k < 3; ++k) {
        double u0 = H[0][0]*Vs[0][k] + H[0][1]*Vs[1][k] + H[0][2]*Vs[2][k];
        double u1 = H[1][0]*Vs[0][k] + H[1][1]*Vs[1][k] + H[1][2]*Vs[2][k];
        double u2 = H[2][0]*Vs[0][k] + H[2][1]*Vs[1][k] + H[2][2]*Vs[2][k];
        double nn = sqrt(u0*u0 + u1*u1 + u2*u2);
        if (k == 2 && (sv[2] <= 1e-10 * sv[0] || nn == 0.0)) {
            u0 = U[1][0]*U[2][1] - U[2][0]*U[1][1];
            u1 = U[2][0]*U[0][1] - U[0][0]*U[2][1];
            u2 = U[0][0]*U[1][1] - U[1][0]*U[0][1];
            nn = sqrt(u0*u0 + u1*u1 + u2*u2);
        }
        const double inv = (nn > 0.0) ? 1.0 / nn : 0.0;
        U[0][k] = u0 * inv; U[1][k] = u1 * inv; U[2][k] = u2 * inv;
    }

    double R[3][3];
    for (int i = 0; i < 3; ++i)
        for (int j = 0; j < 3; ++j)
            R[i][j] = Vs[i][0]*U[j][0] + Vs[i][1]*U[j][1] + Vs[i][2]*U[j][2];
    const double det =
          R[0][0]*(R[1][1]*R[2][2] - R[1][2]*R[2][1])
        - R[0][1]*(R[1][0]*R[2][2] - R[1][2]*R[2][0])
        + R[0][2]*(R[1][0]*R[2][1] - R[1][1]*R[2][0]);
    if (det < 0.0)
        for (int i = 0; i < 3; ++i)
            for (int j = 0; j < 3; ++j)
                R[i][j] -= 2.0 * Vs[i][2] * U[j][2];

    double tv[3];
    for (int i = 0; i < 3; ++i)
        tv[i] = cc[i] - (R[i][0]*cs[0] + R[i][1]*cs[1] + R[i][2]*cs[2]);

    for (int i = 0; i < 3; ++i) {
        for (int j = 0; j < 3; ++j) out[b*16 + i*4 + j] = (float)R[i][j];
        out[b*16 + i*4 + 3] = (float)tv[i];
    }
    out[b*16 + 12] = 0.f; out[b*16 + 13] = 0.f;
    out[b*16 + 14] = 0.f; out[b*16 + 15] = 1.f;
}

extern "C" void kernel_launch(void* const* d_in, const int* in_sizes, int n_in,
                              void* d_out, int out_size, void* d_ws, size_t ws_size,
                              hipStream_t stream)
{
    const float* p_src = (const float*)d_in[0];
    const float* f_src = (const float*)d_in[1];
    const float* p_tgt = (const float*)d_in[2];
    const float* f_tgt = (const float*)d_in[3];
    const float* W     = (const float*)d_in[4];
    const float* bias  = (const float*)d_in[5];
    float* out = (float*)d_out;

    hipMemsetAsync(out, 0, 64 * sizeof(float), stream);

    dim3 grid(NQ / ROWS, NB);   // (64, 4) = 256 blocks
    flash_kernel<<<grid, NTHR, 0, stream>>>(p_src, f_src, p_tgt, f_tgt, W, bias, out);
    svd_kernel<<<1, 64, 0, stream>>>(out);
}

// Round 10
// 327.286 us; speedup vs baseline: 32.5896x; 1.2821x over previous
//
#include <hip/hip_runtime.h>
#include <math.h>

// Problem constants (fixed by setup_inputs)
#define NQ    4096
#define NK    4096
#define DD    256
#define NB    4
#define ROWS  64            // query rows per block
#define NELEM (NB * NK * DD)   // 4,194,304 elements per converted array
#define NTHR  512

typedef __attribute__((ext_vector_type(8))) short          bf16x8;
typedef __attribute__((ext_vector_type(8))) unsigned short u16x8;
typedef __attribute__((ext_vector_type(4))) unsigned short u16x4;
typedef __attribute__((ext_vector_type(4))) float          f32x4;

__device__ __forceinline__ unsigned short f2bf(float x) {
    union { float f; unsigned u; } v; v.f = x;
    unsigned r = v.u + 0x7fffu + ((v.u >> 16) & 1u);   // RN-even
    return (unsigned short)(r >> 16);
}
__device__ __forceinline__ float bf2f(unsigned short h) {
    union { unsigned u; float f; } v; v.u = ((unsigned)h) << 16;
    return v.f;
}

// async global->LDS, 16 B per lane; LDS dest = wave-uniform base + lane*16
__device__ __forceinline__ void gl2lds16(const unsigned short* g, unsigned short* l) {
    __builtin_amdgcn_global_load_lds(
        (const __attribute__((address_space(1))) unsigned int*)g,
        (__attribute__((address_space(3))) unsigned int*)l,
        16, 0, 0);
}

// ---------------------------------------------------------------------------
// Pre-convert f_tgt fp32 -> bf16 hi/lo slabs in d_ws, in the exact LDS image
// layout (slab-major, XOR-swizzle baked in) so the main kernel stages with
// pure linear global_load_lds copies (rule: linear dest + pre-swizzled src).
// Slab (b, hb=key>>7, dsl=d>>6) of [128 keys][64 dims]; image pos within slab
// = (kl*64+dl) ^ ((kl&7)<<3).  hi at ws[pos], lo at ws[NELEM+pos].
// ---------------------------------------------------------------------------
__global__ __launch_bounds__(256)
void convert_kernel(const float* __restrict__ f_tgt, unsigned short* __restrict__ ws)
{
    const int gid = blockIdx.x * 256 + threadIdx.x;     // 0..524287
    const int oct = gid & 31;                           // 8-dim octet in 0..31
    const int bk  = gid >> 5;                           // b*4096+key
    const int key = bk & 4095;
    const int b   = bk >> 12;
    const int d0  = oct * 8;

    const float* src = f_tgt + ((size_t)bk * DD + d0);
    float4 fa = *(const float4*)(src);
    float4 fb = *(const float4*)(src + 4);
    float v[8] = { fa.x, fa.y, fa.z, fa.w, fb.x, fb.y, fb.z, fb.w };
    u16x8 hi, lo;
    #pragma unroll
    for (int e = 0; e < 8; ++e) {
        unsigned short h = f2bf(v[e]);
        hi[e] = h;
        lo[e] = f2bf(v[e] - bf2f(h));
    }
    const int hb  = key >> 7, kl = key & 127;
    const int dsl = d0 >> 6,  dl = d0 & 63;
    const int si  = ((b * 32 + hb) * 4 + dsl);
    const int pos = si * 8192 + ((kl * 64 + dl) ^ ((kl & 7) << 3));
    *(u16x8*)&ws[pos]         = hi;
    *(u16x8*)&ws[NELEM + pos] = lo;
}

// ---------------------------------------------------------------------------
// MFMA flash kernel, split-bf16 3-pass (QhiKhi + QhiKlo + QloKhi).
// Per block: 64 Q-rows. 8 waves = 2 row-groups x 4 key-groups.
// Main loop: 32 key-halves x 4 dim-slices, ring-2 LDS staged via
// global_load_lds from the preconverted slabs (T3-minimal: issue s+1,
// compute s, __syncthreads drains vmcnt). Softmax is PER-WAVE over its own
// 32-key stripe (no cross-wave reductions in the loop); waves merge m/l/pv
// once in the epilogue via l*exp(m_w - m).
// A-side (Qhi+Qlo) held entirely in registers (AGPR-eligible).
// LDS 69 KB -> 2 blocks/CU.
// ---------------------------------------------------------------------------
__global__ __launch_bounds__(NTHR)
void flash_kernel(const float* __restrict__ p_src,
                  const float* __restrict__ f_src,
                  const float* __restrict__ p_tgt,
                  const unsigned short* __restrict__ ws,   // preconverted K
                  const float* __restrict__ W,
                  const float* __restrict__ bias,
                  float* __restrict__ out_acc)
{
    __shared__ __align__(16) unsigned short buf[2][16384];  // 2 x (16K hi + 16K lo)
    __shared__ float fredm[4][ROWS], fredl[4][ROWS], fredp[4][ROWS][3];

    const int t    = threadIdx.x;
    const int lane = t & 63;
    const int wave = __builtin_amdgcn_readfirstlane(t >> 6);
    const int rg   = wave >> 2;        // row-group: rows rg*32..+32
    const int kg   = wave & 3;         // key-group: keys kg*32..+32 per half
    const int l15  = lane & 15;
    const int l4   = lane >> 4;        // 0..3

    // batch->XCD affinity swizzle (heuristic only)
    const int wg   = blockIdx.y * gridDim.x + blockIdx.x;   // 0..255
    const int b    = (wg & 7) >> 1;
    const int rb   = (wg >> 3) + ((wg & 1) << 5);
    const int row0 = rb * ROWS;

    // ---------------- Phase A: Q = f_src @ W^T + bias (fp32 VALU) ----------
    {
        const int rbase = row0 + wave * 8;
        const int c0    = lane * 4;
        float acc[8][4];
        #pragma unroll
        for (int i = 0; i < 8; ++i)
            #pragma unroll
            for (int j = 0; j < 4; ++j) acc[i][j] = 0.f;

        const float* fs = f_src + ((size_t)b * NQ + rbase) * DD;
        const float* Wp = W + (size_t)c0 * DD;
        for (int k = 0; k < DD; k += 4) {
            float4 w0 = *(const float4*)(Wp + 0 * DD + k);
            float4 w1 = *(const float4*)(Wp + 1 * DD + k);
            float4 w2 = *(const float4*)(Wp + 2 * DD + k);
            float4 w3 = *(const float4*)(Wp + 3 * DD + k);
            #pragma unroll
            for (int i = 0; i < 8; ++i) {
                float4 f = *(const float4*)(fs + i * DD + k);
                acc[i][0] += f.x*w0.x + f.y*w0.y + f.z*w0.z + f.w*w0.w;
                acc[i][1] += f.x*w1.x + f.y*w1.y + f.z*w1.z + f.w*w1.w;
                acc[i][2] += f.x*w2.x + f.y*w2.y + f.z*w2.z + f.w*w2.w;
                acc[i][3] += f.x*w3.x + f.y*w3.y + f.z*w3.z + f.w*w3.w;
            }
        }
        float4 bv = *(const float4*)(bias + c0);
        #pragma unroll
        for (int i = 0; i < 8; ++i) {
            const int r = wave * 8 + i;          // local row 0..63
            float q[4] = { acc[i][0] + bv.x, acc[i][1] + bv.y,
                           acc[i][2] + bv.z, acc[i][3] + bv.w };
            u16x4 hi, lo;
            #pragma unroll
            for (int j = 0; j < 4; ++j) {
                unsigned short h = f2bf(q[j]);
                hi[j] = h;
                lo[j] = f2bf(q[j] - bf2f(h));
            }
            const int idx = (r * DD + c0) ^ ((r & 7) << 3);
            *(u16x4*)&buf[0][idx] = hi;          // Qhi image
            *(u16x4*)&buf[1][idx] = lo;          // Qlo image
        }
    }
    __syncthreads();

    // ---------------- A fragments (held in registers for whole kernel) -----
    // 16x16x32 A-frag: lane holds A[m][k], m = lane&15, k = (lane>>4)*8 + e.
    bf16x8 ahi[2][8], alo[2][8];
    #pragma unroll
    for (int rf = 0; rf < 2; ++rf) {
        const int row = rg * 32 + rf * 16 + l15;
        #pragma unroll
        for (int c = 0; c < 8; ++c) {
            const int d   = c * 32 + l4 * 8;
            const int idx = (row * DD + d) ^ ((row & 7) << 3);
            ahi[rf][c] = *(const bf16x8*)&buf[0][idx];
            alo[rf][c] = *(const bf16x8*)&buf[1][idx];
        }
    }
    __syncthreads();   // all frag reads done; buf free for K staging

    // ---------------- per-wave softmax state --------------------------------
    float m_run[2][4], l_run[2][4], pv[2][4][3];
    #pragma unroll
    for (int rf = 0; rf < 2; ++rf)
        #pragma unroll
        for (int j = 0; j < 4; ++j) {
            m_run[rf][j] = -INFINITY; l_run[rf][j] = 0.f;
            pv[rf][j][0] = pv[rf][j][1] = pv[rf][j][2] = 0.f;
        }

    const unsigned short* whi = ws + (size_t)b * 128 * 8192;
    const unsigned short* wlo = whi + NELEM;
    const int soff = (wave * 2) * 512;           // this wave's staging chunk (elems)

    // prologue: stage slab 0 -> buf[0]
    {
        #pragma unroll
        for (int r = 0; r < 2; ++r) {
            gl2lds16(whi + soff + r * 512 + lane * 8, &buf[0][soff + r * 512]);
            gl2lds16(wlo + soff + r * 512 + lane * 8, &buf[0][8192 + soff + r * 512]);
        }
    }
    __syncthreads();   // drains vmcnt -> slab 0 resident

    for (int hb = 0; hb < 32; ++hb) {
        f32x4 acc[2][2];
        #pragma unroll
        for (int rf = 0; rf < 2; ++rf)
            #pragma unroll
            for (int cf = 0; cf < 2; ++cf)
                acc[rf][cf] = (f32x4){0.f, 0.f, 0.f, 0.f};

        #pragma unroll
        for (int dsl = 0; dsl < 4; ++dsl) {
            // ---- issue next slab's loads (land during/after compute) ----
            const int ns = hb * 4 + dsl + 1;
            if (ns < 128) {
                const unsigned short* shi = whi + (size_t)ns * 8192;
                const unsigned short* slo = wlo + (size_t)ns * 8192;
                unsigned short* dst = &buf[(dsl + 1) & 1][0];
                #pragma unroll
                for (int r = 0; r < 2; ++r) {
                    gl2lds16(shi + soff + r * 512 + lane * 8, dst + soff + r * 512);
                    gl2lds16(slo + soff + r * 512 + lane * 8, dst + 8192 + soff + r * 512);
                }
            }
            // ---- compute slab (hb,dsl) from buf[dsl&1] ----
            const unsigned short* bp = &buf[dsl & 1][0];
            #pragma unroll
            for (int kstep = 0; kstep < 2; ++kstep) {
                const int chunk = dsl * 2 + kstep;          // compile-time
                bf16x8 bhi[2], blo[2];
                #pragma unroll
                for (int cf = 0; cf < 2; ++cf) {
                    const int key_l = kg * 32 + cf * 16 + l15;
                    const int dl    = kstep * 32 + l4 * 8;
                    const int idx   = (key_l * 64 + dl) ^ ((key_l & 7) << 3);
                    bhi[cf] = *(const bf16x8*)&bp[idx];
                    blo[cf] = *(const bf16x8*)&bp[8192 + idx];
                }
                #pragma unroll
                for (int rf = 0; rf < 2; ++rf)
                    #pragma unroll
                    for (int cf = 0; cf < 2; ++cf) {
                        acc[rf][cf] = __builtin_amdgcn_mfma_f32_16x16x32_bf16(
                            ahi[rf][chunk], bhi[cf], acc[rf][cf], 0, 0, 0);
                        acc[rf][cf] = __builtin_amdgcn_mfma_f32_16x16x32_bf16(
                            ahi[rf][chunk], blo[cf], acc[rf][cf], 0, 0, 0);
                        acc[rf][cf] = __builtin_amdgcn_mfma_f32_16x16x32_bf16(
                            alo[rf][chunk], bhi[cf], acc[rf][cf], 0, 0, 0);
                    }
            }
            __syncthreads();   // drains vmcnt (next slab ready) + LDS reuse fence
        }

        // ---- per-wave online softmax over this 128-key half (no barriers) ----
        const float* ptb = p_tgt + ((size_t)b * NK + hb * 128 + kg * 32 + l15) * 3;
        const float pt0x = ptb[0],  pt0y = ptb[1],  pt0z = ptb[2];
        const float pt1x = ptb[48], pt1y = ptb[49], pt1z = ptb[50];  // +16 keys

        #pragma unroll
        for (int rf = 0; rf < 2; ++rf) {
            #pragma unroll
            for (int j = 0; j < 4; ++j) {
                float mx = fmaxf(acc[rf][0][j], acc[rf][1][j]);
                mx = fmaxf(mx, __shfl_xor(mx, 1));
                mx = fmaxf(mx, __shfl_xor(mx, 2));
                mx = fmaxf(mx, __shfl_xor(mx, 4));
                mx = fmaxf(mx, __shfl_xor(mx, 8));
                const float mnew = fmaxf(m_run[rf][j], mx);
                const float sc   = __expf(m_run[rf][j] - mnew);
                m_run[rf][j] = mnew;
                const float p0 = __expf(acc[rf][0][j] - mnew);
                const float p1 = __expf(acc[rf][1][j] - mnew);
                l_run[rf][j] = l_run[rf][j] * sc + (p0 + p1);
                pv[rf][j][0] = pv[rf][j][0] * sc + p0 * pt0x + p1 * pt1x;
                pv[rf][j][1] = pv[rf][j][1] * sc + p0 * pt0y + p1 * pt1y;
                pv[rf][j][2] = pv[rf][j][2] * sc + p0 * pt0z + p1 * pt1z;
            }
        }
    }

    // ---------------- epilogue: merge waves' (m,l,pv), then 15 sums ---------
    #pragma unroll
    for (int rf = 0; rf < 2; ++rf)
        #pragma unroll
        for (int j = 0; j < 4; ++j) {
            float lv = l_run[rf][j];
            float p0 = pv[rf][j][0], p1 = pv[rf][j][1], p2 = pv[rf][j][2];
            #pragma unroll
            for (int d = 1; d < 16; d <<= 1) {
                lv += __shfl_xor(lv, d);
                p0 += __shfl_xor(p0, d);
                p1 += __shfl_xor(p1, d);
                p2 += __shfl_xor(p2, d);
            }
            if (l15 == 0) {
                const int row = rg * 32 + rf * 16 + l4 * 4 + j;
                fredm[kg][row] = m_run[rf][j];
                fredl[kg][row] = lv;
                fredp[kg][row][0] = p0; fredp[kg][row][1] = p1; fredp[kg][row][2] = p2;
            }
        }
    __syncthreads();

    if (t < ROWS) {
        float m = fredm[0][t];
        m = fmaxf(m, fredm[1][t]); m = fmaxf(m, fredm[2][t]); m = fmaxf(m, fredm[3][t]);
        float L = 0.f, P0 = 0.f, P1 = 0.f, P2 = 0.f;
        #pragma unroll
        for (int g = 0; g < 4; ++g) {
            const float w = __expf(fredm[g][t] - m);
            L  += fredl[g][t] * w;
            P0 += fredp[g][t][0] * w;
            P1 += fredp[g][t][1] * w;
            P2 += fredp[g][t][2] * w;
        }
        const float pc0 = P0 / L, pc1 = P1 / L, pc2 = P2 / L;

        const float* ps = p_src + ((size_t)b * NQ + row0 + t) * 3;
        const float sp0 = ps[0], sp1 = ps[1], sp2 = ps[2];
        float vals[15];
        vals[0] = sp0; vals[1] = sp1; vals[2] = sp2;
        vals[3] = pc0; vals[4] = pc1; vals[5] = pc2;
        vals[6]  = sp0 * pc0; vals[7]  = sp0 * pc1; vals[8]  = sp0 * pc2;
        vals[9]  = sp1 * pc0; vals[10] = sp1 * pc1; vals[11] = sp1 * pc2;
        vals[12] = sp2 * pc0; vals[13] = sp2 * pc1; vals[14] = sp2 * pc2;
        #pragma unroll
        for (int k2 = 0; k2 < 15; ++k2) {
            float v = vals[k2];
            #pragma unroll
            for (int d = 1; d < 64; d <<= 1) v += __shfl_xor(v, d);
            vals[k2] = v;
        }
        if (t == 0) {
            #pragma unroll
            for (int k2 = 0; k2 < 15; ++k2)
                atomicAdd(&out_acc[b * 16 + k2], vals[k2]);
        }
    }
}

// ---------------------------------------------------------------------------
// Per-batch 3x3 Kabsch: fp64 Jacobi SVD (validated bit-exact in R3-R5)
// ---------------------------------------------------------------------------
__global__ void svd_kernel(float* __restrict__ out)
{
    const int b = threadIdx.x;
    if (b >= NB) return;

    float sbuf[15];
    #pragma unroll
    for (int i = 0; i < 15; ++i) sbuf[i] = out[b * 16 + i];

    const double invN = 1.0 / (double)NQ;
    double Sp[3] = {sbuf[0], sbuf[1], sbuf[2]};
    double Sc[3] = {sbuf[3], sbuf[4], sbuf[5]};
    double H[3][3];
    for (int i = 0; i < 3; ++i)
        for (int j = 0; j < 3; ++j)
            H[i][j] = (double)sbuf[6 + i * 3 + j] - Sp[i] * Sc[j] * invN;
    double cs[3], cc[3];
    for (int i = 0; i < 3; ++i) { cs[i] = Sp[i] * invN; cc[i] = Sc[i] * invN; }

    double A[3][3];
    for (int i = 0; i < 3; ++i)
        for (int j = 0; j < 3; ++j)
            A[i][j] = H[0][i]*H[0][j] + H[1][i]*H[1][j] + H[2][i]*H[2][j];
    double V[3][3] = {{1,0,0},{0,1,0},{0,0,1}};

    for (int sweep = 0; sweep < 30; ++sweep) {
        for (int pp = 0; pp < 3; ++pp) {
            const int p = (pp == 2) ? 1 : 0;
            const int q = (pp == 0) ? 1 : 2;
            const double apq = A[p][q];
            if (fabs(apq) < 1e-300) continue;
            const double app = A[p][p], aqq = A[q][q];
            const double tau = (aqq - app) / (2.0 * apq);
            const double tt  = (tau >= 0.0 ? 1.0 : -1.0) /
                               (fabs(tau) + sqrt(1.0 + tau * tau));
            const double c  = 1.0 / sqrt(1.0 + tt * tt);
            const double sn = tt * c;
            const int r = 3 - p - q;
            const double arp = A[r][p], arq = A[r][q];
            A[p][p] = app - tt * apq;
            A[q][q] = aqq + tt * apq;
            A[p][q] = A[q][p] = 0.0;
            A[r][p] = A[p][r] = c * arp - sn * arq;
            A[r][q] = A[q][r] = sn * arp + c * arq;
            for (int i = 0; i < 3; ++i) {
                const double vip = V[i][p], viq = V[i][q];
                V[i][p] = c * vip - sn * viq;
                V[i][q] = sn * vip + c * viq;
            }
        }
    }

    int idx[3] = {0, 1, 2};
    double lam[3] = {A[0][0], A[1][1], A[2][2]};
    if (lam[idx[0]] < lam[idx[1]]) { int u = idx[0]; idx[0] = idx[1]; idx[1] = u; }
    if (lam[idx[0]] < lam[idx[2]]) { int u = idx[0]; idx[0] = idx[2]; idx[2] = u; }
    if (lam[idx[1]] < lam[idx[2]]) { int u = idx[1]; idx[1] = idx[2]; idx[2] = u; }

    double Vs[3][3], sv[3];
    for (int k = 0; k < 3; ++k) {
        for (int i = 0; i < 3; ++i) Vs[i][k] = V[i][idx[k]];
        const double l2 = lam[idx[k]];
        sv[k] = (l2 > 0.0) ? sqrt(l2) : 0.0;
    }

    double U[3][3];
    for (int k = 0; k < 3; ++k) {
        double u0 = H[0][0]*Vs[0][k] + H[0][1]*Vs[1][k] + H[0][2]*Vs[2][k];
        double u1 = H[1][0]*Vs[0][k] + H[1][1]*Vs[1][k] + H[1][2]*Vs[2][k];
        double u2 = H[2][0]*Vs[0][k] + H[2][1]*Vs[1][k] + H[2][2]*Vs[2][k];
        double nn = sqrt(u0*u0 + u1*u1 + u2*u2);
        if (k == 2 && (sv[2] <= 1e-10 * sv[0] || nn == 0.0)) {
            u0 = U[1][0]*U[2][1] - U[2][0]*U[1][1];
            u1 = U[2][0]*U[0][1] - U[0][0]*U[2][1];
            u2 = U[0][0]*U[1][1] - U[1][0]*U[0][1];
            nn = sqrt(u0*u0 + u1*u1 + u2*u2);
        }
        const double inv = (nn > 0.0) ? 1.0 / nn : 0.0;
        U[0][k] = u0 * inv; U[1][k] = u1 * inv; U[2][k] = u2 * inv;
    }

    double R[3][3];
    for (int i = 0; i < 3; ++i)
        for (int j = 0; j < 3; ++j)
            R[i][j] = Vs[i][0]*U[j][0] + Vs[i][1]*U[j][1] + Vs[i][2]*U[j][2];
    const double det =
          R[0][0]*(R[1][1]*R[2][2] - R[1][2]*R[2][1])
        - R[0][1]*(R[1][0]*R[2][2] - R[1][2]*R[2][0])
        + R[0][2]*(R[1][0]*R[2][1] - R[1][1]*R[2][0]);
    if (det < 0.0)
        for (int i = 0; i < 3; ++i)
            for (int j = 0; j < 3; ++j)
                R[i][j] -= 2.0 * Vs[i][2] * U[j][2];

    double tv[3];
    for (int i = 0; i < 3; ++i)
        tv[i] = cc[i] - (R[i][0]*cs[0] + R[i][1]*cs[1] + R[i][2]*cs[2]);

    for (int i = 0; i < 3; ++i) {
        for (int j = 0; j < 3; ++j) out[b*16 + i*4 + j] = (float)R[i][j];
        out[b*16 + i*4 + 3] = (float)tv[i];
    }
    out[b*16 + 12] = 0.f; out[b*16 + 13] = 0.f;
    out[b*16 + 14] = 0.f; out[b*16 + 15] = 1.f;
}

extern "C" void kernel_launch(void* const* d_in, const int* in_sizes, int n_in,
                              void* d_out, int out_size, void* d_ws, size_t ws_size,
                              hipStream_t stream)
{
    const float* p_src = (const float*)d_in[0];
    const float* f_src = (const float*)d_in[1];
    const float* p_tgt = (const float*)d_in[2];
    const float* f_tgt = (const float*)d_in[3];
    const float* W     = (const float*)d_in[4];
    const float* bias  = (const float*)d_in[5];
    float* out = (float*)d_out;
    unsigned short* ws = (unsigned short*)d_ws;   // needs 2*NELEM*2 B = 16.8 MB

    // accumulators live in d_out[b*16 + 0..14]; zero them (d_out is poisoned)
    hipMemsetAsync(out, 0, 64 * sizeof(float), stream);

    convert_kernel<<<NELEM / 8 / 256, 256, 0, stream>>>(f_tgt, ws);

    dim3 grid(NQ / ROWS, NB);   // (64, 4) = 256 blocks
    flash_kernel<<<grid, NTHR, 0, stream>>>(p_src, f_src, p_tgt, ws, W, bias, out);
    svd_kernel<<<1, 64, 0, stream>>>(out);
}